// Round 3
// baseline (341.082 us; speedup 1.0000x reference)
//
#include <hip/hip_runtime.h>
#include <hip/hip_cooperative_groups.h>

// Sizes fixed by the problem.
#define BS    64
#define KDIM  256   // in_dim
#define ICAP  256   // I = 16*16
#define JCAP  64    // J out-caps
#define D2    32
#define OUTD  2048  // J*D2

typedef short bf16x8 __attribute__((ext_vector_type(8)));
typedef float f32x4  __attribute__((ext_vector_type(4)));

static __device__ __forceinline__ float bf2f(unsigned u16) {
  union { unsigned u; float f; } v; v.u = u16 << 16; return v.f;
}
static __device__ __forceinline__ unsigned short f2bf(float x) {
  union { float f; unsigned u; } v; v.f = x;
  unsigned r = v.u + 0x7fffu + ((v.u >> 16) & 1u);
  return (unsigned short)(r >> 16);
}

// ---------------------------------------------------------------------------
// mega (cooperative, single launch): 256 blocks = (b, q), 512 threads.
//  P1: x[b] f32 -> xKI bf16 (cast) + xT bf16 (transpose)   unit (b, k-quarter)
//  P2: c0 = softmax_j(Binit) -> cm bf16 [b][j][i] + cpart  unit (b, i-quarter)
//  grid.sync
//  pass 1..3:
//   A (unit b, j-quarter): Yt[16j][256k] = xKI*c (MFMA, full k);
//      s[jd] = W.Yt + csum*Wb; squash -> v (pass3: write out, done);
//      U[j][k] = v.W as bf16 hi+lo -> global.       [1 sync]
//   B (unit b, i-quarter): db = xT*U (MFMA hi+lo); b += db+ub (regs);
//      softmax_j -> cm + cpart.                     [1 sync]
// ---------------------------------------------------------------------------
__global__ __launch_bounds__(512) void mega(
    const float* __restrict__ x,            // [BS][KDIM][ICAP] f32
    const float* __restrict__ Binit,        // [BS][JCAP][ICAP] f32
    const float* __restrict__ W,            // [OUTD][KDIM] f32
    const float* __restrict__ Wb,           // [OUTD] f32
    unsigned short* __restrict__ xT,        // [BS][ICAP][KDIM] bf16
    unsigned short* __restrict__ xKI,       // [BS][KDIM][ICAP] bf16
    unsigned short* __restrict__ cm,        // [BS][JCAP][ICAP] bf16
    unsigned short* __restrict__ Uhi,       // [BS][JCAP][KDIM] bf16
    unsigned short* __restrict__ Ulo,       // [BS][JCAP][KDIM] bf16
    float* __restrict__ cpart,              // [BS][4][JCAP] f32
    float* __restrict__ ubg,                // [BS][JCAP] f32
    float* __restrict__ outp)               // [BS][OUTD] f32
{
  __shared__ union {
    float xs[64][260];                                          // P1 transpose
    struct { float Bs[64][68]; float mx[64]; float inv[64]; } p2;
    struct { float yt[16][260]; float vls[16][33]; } a;         // phase A
    float dbl[64][65];                                          // phase B
  } sm;

  cooperative_groups::grid_group grid = cooperative_groups::this_grid();

  const int t   = threadIdx.x;        // 0..511
  const int u   = blockIdx.x;         // 0..255
  const int b   = u >> 2;
  const int q   = u & 3;
  const int w   = t >> 6;             // wave 0..7
  const int l15 = t & 15;
  const int lhi = (t >> 4) & 3;

  // ---------------- P1: x prep (q = k-quarter) ----------------
  {
    const int k0  = q * 64;
    const int r   = t >> 3;             // 0..63
    const int c32 = (t & 7) * 32;
    const float* src = x + ((size_t)(b * KDIM + k0 + r)) * ICAP + c32;
    f32x4 vv[8];
#pragma unroll
    for (int e = 0; e < 8; ++e) vv[e] = *(const f32x4*)(src + e * 4);
    {   // xKI straight cast (no LDS round trip)
      unsigned pk[16];
      const float* fv = (const float*)vv;
#pragma unroll
      for (int h = 0; h < 16; ++h)
        pk[h] = (unsigned)f2bf(fv[2 * h]) | ((unsigned)f2bf(fv[2 * h + 1]) << 16);
      unsigned short* dst = xKI + ((size_t)(b * KDIM + k0 + r)) * ICAP + c32;
      *(uint4*)(dst)      = *(uint4*)&pk[0];
      *(uint4*)(dst + 8)  = *(uint4*)&pk[4];
      *(uint4*)(dst + 16) = *(uint4*)&pk[8];
      *(uint4*)(dst + 24) = *(uint4*)&pk[12];
    }
#pragma unroll
    for (int e = 0; e < 8; ++e) *(f32x4*)&sm.xs[r][c32 + e * 4] = vv[e];
  }
  __syncthreads();
  {   // xT transpose out of LDS
    const int k0 = q * 64;
    const int i  = t >> 1;              // 0..255
    const int kh = (t & 1) * 32;
    unsigned pk[16];
#pragma unroll
    for (int h = 0; h < 16; ++h)
      pk[h] = (unsigned)f2bf(sm.xs[kh + 2 * h][i]) |
              ((unsigned)f2bf(sm.xs[kh + 2 * h + 1][i]) << 16);
    unsigned short* dst = xT + ((size_t)(b * ICAP + i)) * KDIM + k0 + kh;
    *(uint4*)(dst)      = *(uint4*)&pk[0];
    *(uint4*)(dst + 8)  = *(uint4*)&pk[4];
    *(uint4*)(dst + 16) = *(uint4*)&pk[8];
    *(uint4*)(dst + 24) = *(uint4*)&pk[12];
  }
  __syncthreads();

  // ---------------- P2: Binit softmax (q = i-quarter) ----------------
  {
    const int i0 = q * 64;
    {
      const int j = t >> 3, c8 = (t & 7) * 8;
      const float* src = Binit + ((size_t)(b * JCAP + j)) * ICAP + i0 + c8;
      *(f32x4*)&sm.p2.Bs[j][c8]     = *(const f32x4*)src;
      *(f32x4*)&sm.p2.Bs[j][c8 + 4] = *(const f32x4*)(src + 4);
    }
    __syncthreads();
    if (t < 64) {
      float m = -3.0e38f;
      for (int j = 0; j < 64; ++j) m = fmaxf(m, sm.p2.Bs[j][t]);
      float se = 0.f;
      for (int j = 0; j < 64; ++j) se += __expf(sm.p2.Bs[j][t] - m);
      sm.p2.mx[t] = m; sm.p2.inv[t] = 1.0f / se;
    }
    __syncthreads();
    {
      const int j = t >> 3, c8 = (t & 7) * 8;
      float csump = 0.f;
      unsigned pk[4];
#pragma unroll
      for (int h = 0; h < 4; ++h) {
        const int ia = c8 + 2 * h, ib2 = c8 + 2 * h + 1;
        float lo = __expf(sm.p2.Bs[j][ia] - sm.p2.mx[ia]) * sm.p2.inv[ia];
        float hi = __expf(sm.p2.Bs[j][ib2] - sm.p2.mx[ib2]) * sm.p2.inv[ib2];
        csump += lo + hi;
        pk[h] = (unsigned)f2bf(lo) | ((unsigned)f2bf(hi) << 16);
      }
      uint4 sv; sv.x = pk[0]; sv.y = pk[1]; sv.z = pk[2]; sv.w = pk[3];
      *(uint4*)(cm + ((size_t)(b * JCAP + j)) * ICAP + i0 + c8) = sv;
      csump += __shfl_xor(csump, 1, 64);
      csump += __shfl_xor(csump, 2, 64);
      csump += __shfl_xor(csump, 4, 64);
      if ((t & 7) == 0) cpart[((size_t)(b * 4 + q)) * JCAP + j] = csump;
    }
  }
  grid.sync();

  // ---------------- routing passes ----------------
  float blogreg[8];

  for (int pass = 1; pass <= 3; ++pass) {
    // ======== phase A (unit b, jq = q) ========
    {   // Y MFMA: Yt[jl][k] = sum_i xKI[k][i] * c[jq*16+jl][i]
      f32x4 acc0 = (f32x4){0.f, 0.f, 0.f, 0.f};
      f32x4 acc1 = (f32x4){0.f, 0.f, 0.f, 0.f};
      const unsigned short* Ar =
          xKI + ((size_t)(b * KDIM + w * 32 + l15)) * ICAP + lhi * 8;
      const unsigned short* Br =
          cm + ((size_t)(b * JCAP + q * 16 + l15)) * ICAP + lhi * 8;
#pragma unroll
      for (int kk = 0; kk < 8; ++kk) {
        bf16x8 bfr = *(const bf16x8*)(Br + kk * 32);
        bf16x8 a0  = *(const bf16x8*)(Ar + kk * 32);
        bf16x8 a1  = *(const bf16x8*)(Ar + (size_t)16 * ICAP + kk * 32);
        acc0 = __builtin_amdgcn_mfma_f32_16x16x32_bf16(a0, bfr, acc0, 0, 0, 0);
        acc1 = __builtin_amdgcn_mfma_f32_16x16x32_bf16(a1, bfr, acc1, 0, 0, 0);
      }
      // D: col(l15)=j-local, row(lhi*4+r)=k-local within m-tile
      *(f32x4*)&sm.a.yt[l15][w * 32 + lhi * 4]      = acc0;
      *(f32x4*)&sm.a.yt[l15][w * 32 + 16 + lhi * 4] = acc1;
    }
    __syncthreads();

    // s + squash (one jd per thread)
    {
      const int jl = t >> 5;           // 0..15
      const int d  = t & 31;
      const int jg = q * 16 + jl;
      const int jd = jg * 32 + d;
      float s = 0.f;
      const float* wrow = W + (size_t)jd * KDIM;
      const float* yrow = &sm.a.yt[jl][0];
#pragma unroll 4
      for (int k8 = 0; k8 < 32; ++k8) {
        f32x4 w0 = *(const f32x4*)(wrow + k8 * 8);
        f32x4 w1 = *(const f32x4*)(wrow + k8 * 8 + 4);
        f32x4 y0 = *(const f32x4*)(yrow + k8 * 8);
        f32x4 y1 = *(const f32x4*)(yrow + k8 * 8 + 4);
        s += w0.x * y0.x + w0.y * y0.y + w0.z * y0.z + w0.w * y0.w;
        s += w1.x * y1.x + w1.y * y1.y + w1.z * y1.z + w1.w * y1.w;
      }
      float cs = cpart[((size_t)(b * 4 + 0)) * JCAP + jg] +
                 cpart[((size_t)(b * 4 + 1)) * JCAP + jg] +
                 cpart[((size_t)(b * 4 + 2)) * JCAP + jg] +
                 cpart[((size_t)(b * 4 + 3)) * JCAP + jg];
      const float wbv = Wb[jd];
      s += cs * wbv;
      float sq = s * s;
      sq += __shfl_xor(sq, 1, 64);
      sq += __shfl_xor(sq, 2, 64);
      sq += __shfl_xor(sq, 4, 64);
      sq += __shfl_xor(sq, 8, 64);
      sq += __shfl_xor(sq, 16, 64);
      const float scale = (sq / (1.0f + sq)) / sqrtf(sq + 1e-8f);
      const float v = scale * s;
      if (pass == 3) {
        outp[(size_t)b * OUTD + jd] = v;
      } else {
        sm.a.vls[jl][d] = v;
        float up = v * wbv;
        up += __shfl_xor(up, 1, 64);
        up += __shfl_xor(up, 2, 64);
        up += __shfl_xor(up, 4, 64);
        up += __shfl_xor(up, 8, 64);
        up += __shfl_xor(up, 16, 64);
        if (d == 0) ubg[(size_t)b * JCAP + jg] = up;
      }
    }
    if (pass == 3) return;
    __syncthreads();

    // U: U[jg][k] = sum_d v[jg][d]*W[jg*32+d][k], bf16 hi+lo
    {
      const int jl  = t >> 5;
      const int jg  = q * 16 + jl;
      const int kc8 = (t & 31) * 8;
      float acc[8] = {0.f, 0.f, 0.f, 0.f, 0.f, 0.f, 0.f, 0.f};
      const float* wb2 = W + (size_t)(jg * 32) * KDIM + kc8;
#pragma unroll 4
      for (int dd = 0; dd < 32; ++dd) {
        const float vd = sm.a.vls[jl][dd];
        f32x4 w0 = *(const f32x4*)(wb2 + (size_t)dd * KDIM);
        f32x4 w1 = *(const f32x4*)(wb2 + (size_t)dd * KDIM + 4);
        acc[0] += vd * w0.x; acc[1] += vd * w0.y;
        acc[2] += vd * w0.z; acc[3] += vd * w0.w;
        acc[4] += vd * w1.x; acc[5] += vd * w1.y;
        acc[6] += vd * w1.z; acc[7] += vd * w1.w;
      }
      unsigned ph[4], pl[4];
#pragma unroll
      for (int h = 0; h < 4; ++h) {
        unsigned short h0 = f2bf(acc[2 * h]), h1 = f2bf(acc[2 * h + 1]);
        float r0 = acc[2 * h] - bf2f(h0), r1 = acc[2 * h + 1] - bf2f(h1);
        ph[h] = (unsigned)h0 | ((unsigned)h1 << 16);
        pl[h] = (unsigned)f2bf(r0) | ((unsigned)f2bf(r1) << 16);
      }
      size_t off = ((size_t)(b * JCAP + jg)) * KDIM + kc8;
      uint4 qh; qh.x = ph[0]; qh.y = ph[1]; qh.z = ph[2]; qh.w = ph[3];
      uint4 ql; ql.x = pl[0]; ql.y = pl[1]; ql.z = pl[2]; ql.w = pl[3];
      *(uint4*)(Uhi + off) = qh;
      *(uint4*)(Ulo + off) = ql;
    }
    grid.sync();

    // ======== phase B: db + softmax (unit b, iq = q) ========
    {
      const int i0b = q * 64;
      const int mt  = w & 3, nh = w >> 2;
      f32x4 acc[2];
      acc[0] = (f32x4){0.f, 0.f, 0.f, 0.f};
      acc[1] = (f32x4){0.f, 0.f, 0.f, 0.f};
      const unsigned short* Ar =
          xT + ((size_t)(b * ICAP + i0b + mt * 16 + l15)) * KDIM + lhi * 8;
      const unsigned short* Bh =
          Uhi + ((size_t)(b * JCAP + nh * 32 + l15)) * KDIM + lhi * 8;
      const unsigned short* Bl =
          Ulo + ((size_t)(b * JCAP + nh * 32 + l15)) * KDIM + lhi * 8;
#pragma unroll
      for (int kk = 0; kk < 8; ++kk) {
        bf16x8 a = *(const bf16x8*)(Ar + kk * 32);
#pragma unroll
        for (int n = 0; n < 2; ++n) {
          bf16x8 bh = *(const bf16x8*)(Bh + (size_t)(n * 16) * KDIM + kk * 32);
          acc[n] = __builtin_amdgcn_mfma_f32_16x16x32_bf16(a, bh, acc[n], 0, 0, 0);
          bf16x8 bl = *(const bf16x8*)(Bl + (size_t)(n * 16) * KDIM + kk * 32);
          acc[n] = __builtin_amdgcn_mfma_f32_16x16x32_bf16(a, bl, acc[n], 0, 0, 0);
        }
      }
#pragma unroll
      for (int n = 0; n < 2; ++n)
#pragma unroll
        for (int r = 0; r < 4; ++r)
          sm.dbl[mt * 16 + lhi * 4 + r][nh * 32 + n * 16 + l15] = acc[n][r];
    }
    __syncthreads();
    {   // softmax over j (in-register b-logits)
      const int i0b = q * 64;
      const int il = t >> 3, jc = (t & 7) * 8;
      const int ig = i0b + il;
      f32x4 ub0 = *(const f32x4*)(ubg + (size_t)b * JCAP + jc);
      f32x4 ub1 = *(const f32x4*)(ubg + (size_t)b * JCAP + jc + 4);
      const float ubv[8] = {ub0.x, ub0.y, ub0.z, ub0.w, ub1.x, ub1.y, ub1.z, ub1.w};
      float bn[8];
#pragma unroll
      for (int e = 0; e < 8; ++e) {
        float bold = (pass == 1)
            ? Binit[((size_t)(b * JCAP + jc + e)) * ICAP + ig]
            : blogreg[e];
        bn[e] = bold + sm.dbl[il][jc + e] + ubv[e];
        blogreg[e] = bn[e];
      }
      float mx = bn[0];
#pragma unroll
      for (int e = 1; e < 8; ++e) mx = fmaxf(mx, bn[e]);
      mx = fmaxf(mx, __shfl_xor(mx, 1, 64));
      mx = fmaxf(mx, __shfl_xor(mx, 2, 64));
      mx = fmaxf(mx, __shfl_xor(mx, 4, 64));
      float e8[8], se = 0.f;
#pragma unroll
      for (int e = 0; e < 8; ++e) { e8[e] = __expf(bn[e] - mx); se += e8[e]; }
      se += __shfl_xor(se, 1, 64);
      se += __shfl_xor(se, 2, 64);
      se += __shfl_xor(se, 4, 64);
      const float inv = 1.0f / se;
#pragma unroll
      for (int e = 0; e < 8; ++e) sm.dbl[il][jc + e] = e8[e] * inv;
    }
    __syncthreads();
    {   // transpose-pack c -> cm + cpart
      const int i0b = q * 64;
      const int j2 = t >> 3, ic8 = (t & 7) * 8;
      float csump = 0.f;
      unsigned pk[4];
#pragma unroll
      for (int h = 0; h < 4; ++h) {
        float lo = sm.dbl[ic8 + 2 * h][j2];
        float hi = sm.dbl[ic8 + 2 * h + 1][j2];
        csump += lo + hi;
        pk[h] = (unsigned)f2bf(lo) | ((unsigned)f2bf(hi) << 16);
      }
      uint4 sv; sv.x = pk[0]; sv.y = pk[1]; sv.z = pk[2]; sv.w = pk[3];
      *(uint4*)(cm + ((size_t)(b * JCAP + j2)) * ICAP + i0b + ic8) = sv;
      csump += __shfl_xor(csump, 1, 64);
      csump += __shfl_xor(csump, 2, 64);
      csump += __shfl_xor(csump, 4, 64);
      if ((t & 7) == 0) cpart[((size_t)(b * 4 + q)) * JCAP + j2] = csump;
    }
    grid.sync();
  }
}

// ---------------------------------------------------------------------------
extern "C" void kernel_launch(void* const* d_in, const int* in_sizes, int n_in,
                              void* d_out, int out_size, void* d_ws, size_t ws_size,
                              hipStream_t stream) {
  const float* x  = (const float*)d_in[0];
  const float* bi = (const float*)d_in[1];
  const float* W  = (const float*)d_in[2];
  const float* Wb = (const float*)d_in[3];
  float* out = (float*)d_out;

  char* ws = (char*)d_ws;
  const size_t MiB = 1024 * 1024;
  unsigned short* xT  = (unsigned short*)(ws + 0 * MiB);    // 8 MiB
  unsigned short* xKI = (unsigned short*)(ws + 8 * MiB);    // 8 MiB
  unsigned short* cm  = (unsigned short*)(ws + 16 * MiB);   // 2 MiB
  unsigned short* Uhi = (unsigned short*)(ws + 18 * MiB);   // 2 MiB
  unsigned short* Ulo = (unsigned short*)(ws + 20 * MiB);   // 2 MiB
  float* cpart        = (float*)(ws + 22 * MiB);            // 64 KiB
  float* ubg          = (float*)(ws + 23 * MiB);            // 16 KiB

  void* args[] = {(void*)&x, (void*)&bi, (void*)&W, (void*)&Wb,
                  (void*)&xT, (void*)&xKI, (void*)&cm, (void*)&Uhi,
                  (void*)&Ulo, (void*)&cpart, (void*)&ubg, (void*)&out};
  hipLaunchCooperativeKernel((void*)mega, dim3(256), dim3(512), args, 0, stream);
}

// Round 4
// 221.399 us; speedup vs baseline: 1.5406x; 1.5406x over previous
//
#include <hip/hip_runtime.h>

// Sizes fixed by the problem.
#define BS    64
#define KDIM  256   // in_dim
#define ICAP  256   // I = 16*16
#define JCAP  64    // J out-caps
#define D2    32
#define OUTD  2048  // J*D2

typedef short bf16x8 __attribute__((ext_vector_type(8)));
typedef float f32x4  __attribute__((ext_vector_type(4)));

static __device__ __forceinline__ float bf2f(unsigned u16) {
  union { unsigned u; float f; } v; v.u = u16 << 16; return v.f;
}
static __device__ __forceinline__ unsigned short f2bf(float x) {
  union { float f; unsigned u; } v; v.f = x;
  unsigned r = v.u + 0x7fffu + ((v.u >> 16) & 1u);
  return (unsigned short)(r >> 16);
}

// 4-block group barrier: monotone counter per group, agent-scope acq/rel.
// Group = blocks {b, b+64, b+128, b+192}; counter zeroed by memset each launch.
static __device__ __forceinline__ void group_barrier(int* cnt, int target) {
  __syncthreads();
  if (threadIdx.x == 0) {
    __hip_atomic_fetch_add(cnt, 1, __ATOMIC_ACQ_REL, __HIP_MEMORY_SCOPE_AGENT);
    while (__hip_atomic_load(cnt, __ATOMIC_ACQUIRE, __HIP_MEMORY_SCOPE_AGENT) < target)
      __builtin_amdgcn_s_sleep(4);
  }
  __syncthreads();
}

// ---------------------------------------------------------------------------
// mega: 256 blocks = (b = bid&63, q = bid>>6), 512 threads. Single launch.
//  P1 (q = k-quarter): x f32 -> xKI bf16 + xT bf16.
//  P2 (q = i-quarter): c0 = softmax_j(Binit) -> cm bf16 [b][j][i] + cpart.
//  [group barrier]
//  pass 1..3:
//   A (q = j-quarter): Yt[16j][256k] = xKI*c (MFMA);
//      s[jd] = W.Yt + csum*Wb; squash -> v (pass3: write out, return);
//      U[j][k] = v.W as bf16 hi+lo -> global.   [group barrier]
//   B (q = i-quarter): db = xT*U (MFMA hi+lo); logits += db+ub (regs);
//      softmax_j -> cm + cpart.                 [group barrier]
// ---------------------------------------------------------------------------
__global__ __launch_bounds__(512) void mega(
    const float* __restrict__ x,            // [BS][KDIM][ICAP] f32
    const float* __restrict__ Binit,        // [BS][JCAP][ICAP] f32
    const float* __restrict__ W,            // [OUTD][KDIM] f32
    const float* __restrict__ Wb,           // [OUTD] f32
    unsigned short* __restrict__ xT,        // [BS][ICAP][KDIM] bf16
    unsigned short* __restrict__ xKI,       // [BS][KDIM][ICAP] bf16
    unsigned short* __restrict__ cm,        // [BS][JCAP][ICAP] bf16
    unsigned short* __restrict__ Uhi,       // [BS][JCAP][KDIM] bf16
    unsigned short* __restrict__ Ulo,       // [BS][JCAP][KDIM] bf16
    float* __restrict__ cpart,              // [BS][4][JCAP] f32
    float* __restrict__ ubg,                // [BS][JCAP] f32
    int* __restrict__ cnt,                  // [BS][16] barrier counters
    float* __restrict__ outp)               // [BS][OUTD] f32
{
  __shared__ union {
    float xs[64][260];                                          // P1 transpose
    struct { float Bs[64][68]; float mx[64]; float inv[64]; } p2;
    struct { float yt[16][260]; float vls[16][33]; } a;         // phase A
    float dbl[64][65];                                          // phase B
  } sm;

  const int t   = threadIdx.x;        // 0..511
  const int u   = blockIdx.x;         // 0..255
  const int b   = u & 63;
  const int q   = u >> 6;
  const int w   = t >> 6;             // wave 0..7
  const int l15 = t & 15;
  const int lhi = (t >> 4) & 3;
  int* gcnt = cnt + b * 16;

  // ---------------- P1: x prep (q = k-quarter) ----------------
  {
    const int k0  = q * 64;
    const int r   = t >> 3;             // 0..63
    const int c32 = (t & 7) * 32;
    const float* src = x + ((size_t)(b * KDIM + k0 + r)) * ICAP + c32;
    f32x4 vv[8];
#pragma unroll
    for (int e = 0; e < 8; ++e) vv[e] = *(const f32x4*)(src + e * 4);
    {   // xKI straight cast (no LDS round trip)
      unsigned pk[16];
      const float* fv = (const float*)vv;
#pragma unroll
      for (int h = 0; h < 16; ++h)
        pk[h] = (unsigned)f2bf(fv[2 * h]) | ((unsigned)f2bf(fv[2 * h + 1]) << 16);
      unsigned short* dst = xKI + ((size_t)(b * KDIM + k0 + r)) * ICAP + c32;
      *(uint4*)(dst)      = *(uint4*)&pk[0];
      *(uint4*)(dst + 8)  = *(uint4*)&pk[4];
      *(uint4*)(dst + 16) = *(uint4*)&pk[8];
      *(uint4*)(dst + 24) = *(uint4*)&pk[12];
    }
#pragma unroll
    for (int e = 0; e < 8; ++e) *(f32x4*)&sm.xs[r][c32 + e * 4] = vv[e];
  }
  __syncthreads();
  {   // xT transpose out of LDS
    const int k0 = q * 64;
    const int i  = t >> 1;              // 0..255
    const int kh = (t & 1) * 32;
    unsigned pk[16];
#pragma unroll
    for (int h = 0; h < 16; ++h)
      pk[h] = (unsigned)f2bf(sm.xs[kh + 2 * h][i]) |
              ((unsigned)f2bf(sm.xs[kh + 2 * h + 1][i]) << 16);
    unsigned short* dst = xT + ((size_t)(b * ICAP + i)) * KDIM + k0 + kh;
    *(uint4*)(dst)      = *(uint4*)&pk[0];
    *(uint4*)(dst + 8)  = *(uint4*)&pk[4];
    *(uint4*)(dst + 16) = *(uint4*)&pk[8];
    *(uint4*)(dst + 24) = *(uint4*)&pk[12];
  }
  __syncthreads();

  // ---------------- P2: Binit softmax (q = i-quarter) ----------------
  {
    const int i0 = q * 64;
    {
      const int j = t >> 3, c8 = (t & 7) * 8;
      const float* src = Binit + ((size_t)(b * JCAP + j)) * ICAP + i0 + c8;
      *(f32x4*)&sm.p2.Bs[j][c8]     = *(const f32x4*)src;
      *(f32x4*)&sm.p2.Bs[j][c8 + 4] = *(const f32x4*)(src + 4);
    }
    __syncthreads();
    if (t < 64) {
      float m = -3.0e38f;
      for (int j = 0; j < 64; ++j) m = fmaxf(m, sm.p2.Bs[j][t]);
      float se = 0.f;
      for (int j = 0; j < 64; ++j) se += __expf(sm.p2.Bs[j][t] - m);
      sm.p2.mx[t] = m; sm.p2.inv[t] = 1.0f / se;
    }
    __syncthreads();
    {
      const int j = t >> 3, c8 = (t & 7) * 8;
      float csump = 0.f;
      unsigned pk[4];
#pragma unroll
      for (int h = 0; h < 4; ++h) {
        const int ia = c8 + 2 * h, ib2 = c8 + 2 * h + 1;
        float lo = __expf(sm.p2.Bs[j][ia] - sm.p2.mx[ia]) * sm.p2.inv[ia];
        float hi = __expf(sm.p2.Bs[j][ib2] - sm.p2.mx[ib2]) * sm.p2.inv[ib2];
        csump += lo + hi;
        pk[h] = (unsigned)f2bf(lo) | ((unsigned)f2bf(hi) << 16);
      }
      uint4 sv; sv.x = pk[0]; sv.y = pk[1]; sv.z = pk[2]; sv.w = pk[3];
      *(uint4*)(cm + ((size_t)(b * JCAP + j)) * ICAP + i0 + c8) = sv;
      csump += __shfl_xor(csump, 1, 64);
      csump += __shfl_xor(csump, 2, 64);
      csump += __shfl_xor(csump, 4, 64);
      if ((t & 7) == 0) cpart[((size_t)(b * 4 + q)) * JCAP + j] = csump;
    }
  }
  group_barrier(gcnt, 4);

  // ---------------- routing passes ----------------
  float blogreg[8];

  for (int pass = 1; pass <= 3; ++pass) {
    // ======== phase A (unit b, jq = q) ========
    {   // Y MFMA: Yt[jl][k] = sum_i xKI[k][i] * c[jq*16+jl][i]
      f32x4 acc0 = (f32x4){0.f, 0.f, 0.f, 0.f};
      f32x4 acc1 = (f32x4){0.f, 0.f, 0.f, 0.f};
      const unsigned short* Ar =
          xKI + ((size_t)(b * KDIM + w * 32 + l15)) * ICAP + lhi * 8;
      const unsigned short* Br =
          cm + ((size_t)(b * JCAP + q * 16 + l15)) * ICAP + lhi * 8;
#pragma unroll
      for (int kk = 0; kk < 8; ++kk) {
        bf16x8 bfr = *(const bf16x8*)(Br + kk * 32);
        bf16x8 a0  = *(const bf16x8*)(Ar + kk * 32);
        bf16x8 a1  = *(const bf16x8*)(Ar + (size_t)16 * ICAP + kk * 32);
        acc0 = __builtin_amdgcn_mfma_f32_16x16x32_bf16(a0, bfr, acc0, 0, 0, 0);
        acc1 = __builtin_amdgcn_mfma_f32_16x16x32_bf16(a1, bfr, acc1, 0, 0, 0);
      }
      *(f32x4*)&sm.a.yt[l15][w * 32 + lhi * 4]      = acc0;
      *(f32x4*)&sm.a.yt[l15][w * 32 + 16 + lhi * 4] = acc1;
    }
    __syncthreads();

    // s + squash (one jd per thread owns (jl, d))
    {
      const int jl = t >> 5;           // 0..15
      const int d  = t & 31;
      const int jg = q * 16 + jl;
      const int jd = jg * 32 + d;
      float s = 0.f;
      const float* wrow = W + (size_t)jd * KDIM;
      const float* yrow = &sm.a.yt[jl][0];
#pragma unroll 4
      for (int k8 = 0; k8 < 32; ++k8) {
        f32x4 w0 = *(const f32x4*)(wrow + k8 * 8);
        f32x4 w1 = *(const f32x4*)(wrow + k8 * 8 + 4);
        f32x4 y0 = *(const f32x4*)(yrow + k8 * 8);
        f32x4 y1 = *(const f32x4*)(yrow + k8 * 8 + 4);
        s += w0.x * y0.x + w0.y * y0.y + w0.z * y0.z + w0.w * y0.w;
        s += w1.x * y1.x + w1.y * y1.y + w1.z * y1.z + w1.w * y1.w;
      }
      float cs = cpart[((size_t)(b * 4 + 0)) * JCAP + jg] +
                 cpart[((size_t)(b * 4 + 1)) * JCAP + jg] +
                 cpart[((size_t)(b * 4 + 2)) * JCAP + jg] +
                 cpart[((size_t)(b * 4 + 3)) * JCAP + jg];
      const float wbv = Wb[jd];
      s += cs * wbv;
      float sq = s * s;
      sq += __shfl_xor(sq, 1, 64);
      sq += __shfl_xor(sq, 2, 64);
      sq += __shfl_xor(sq, 4, 64);
      sq += __shfl_xor(sq, 8, 64);
      sq += __shfl_xor(sq, 16, 64);
      const float scale = (sq / (1.0f + sq)) / sqrtf(sq + 1e-8f);
      const float v = scale * s;
      if (pass == 3) {
        outp[(size_t)b * OUTD + jd] = v;
      } else {
        sm.a.vls[jl][d] = v;
        float up = v * wbv;
        up += __shfl_xor(up, 1, 64);
        up += __shfl_xor(up, 2, 64);
        up += __shfl_xor(up, 4, 64);
        up += __shfl_xor(up, 8, 64);
        up += __shfl_xor(up, 16, 64);
        if (d == 0) ubg[(size_t)b * JCAP + jg] = up;
      }
    }
    if (pass == 3) return;
    __syncthreads();

    // U: U[jg][k] = sum_d v[jg][d]*W[jg*32+d][k], bf16 hi+lo
    {
      const int jl  = t >> 5;
      const int jg  = q * 16 + jl;
      const int kc8 = (t & 31) * 8;
      float acc[8] = {0.f, 0.f, 0.f, 0.f, 0.f, 0.f, 0.f, 0.f};
      const float* wb2 = W + (size_t)(jg * 32) * KDIM + kc8;
#pragma unroll 4
      for (int dd = 0; dd < 32; ++dd) {
        const float vd = sm.a.vls[jl][dd];
        f32x4 w0 = *(const f32x4*)(wb2 + (size_t)dd * KDIM);
        f32x4 w1 = *(const f32x4*)(wb2 + (size_t)dd * KDIM + 4);
        acc[0] += vd * w0.x; acc[1] += vd * w0.y;
        acc[2] += vd * w0.z; acc[3] += vd * w0.w;
        acc[4] += vd * w1.x; acc[5] += vd * w1.y;
        acc[6] += vd * w1.z; acc[7] += vd * w1.w;
      }
      unsigned ph[4], pl[4];
#pragma unroll
      for (int h = 0; h < 4; ++h) {
        unsigned short h0 = f2bf(acc[2 * h]), h1 = f2bf(acc[2 * h + 1]);
        float r0 = acc[2 * h] - bf2f(h0), r1 = acc[2 * h + 1] - bf2f(h1);
        ph[h] = (unsigned)h0 | ((unsigned)h1 << 16);
        pl[h] = (unsigned)f2bf(r0) | ((unsigned)f2bf(r1) << 16);
      }
      size_t off = ((size_t)(b * JCAP + jg)) * KDIM + kc8;
      uint4 qh; qh.x = ph[0]; qh.y = ph[1]; qh.z = ph[2]; qh.w = ph[3];
      uint4 ql; ql.x = pl[0]; ql.y = pl[1]; ql.z = pl[2]; ql.w = pl[3];
      *(uint4*)(Uhi + off) = qh;
      *(uint4*)(Ulo + off) = ql;
    }
    group_barrier(gcnt, 4 * (2 * pass));      // 8, 16

    // ======== phase B: db + softmax (unit b, iq = q) ========
    {
      const int i0b = q * 64;
      const int mt  = w & 3, nh = w >> 2;
      f32x4 acc[2];
      acc[0] = (f32x4){0.f, 0.f, 0.f, 0.f};
      acc[1] = (f32x4){0.f, 0.f, 0.f, 0.f};
      const unsigned short* Ar =
          xT + ((size_t)(b * ICAP + i0b + mt * 16 + l15)) * KDIM + lhi * 8;
      const unsigned short* Bh =
          Uhi + ((size_t)(b * JCAP + nh * 32 + l15)) * KDIM + lhi * 8;
      const unsigned short* Bl =
          Ulo + ((size_t)(b * JCAP + nh * 32 + l15)) * KDIM + lhi * 8;
#pragma unroll
      for (int kk = 0; kk < 8; ++kk) {
        bf16x8 a = *(const bf16x8*)(Ar + kk * 32);
#pragma unroll
        for (int n = 0; n < 2; ++n) {
          bf16x8 bh = *(const bf16x8*)(Bh + (size_t)(n * 16) * KDIM + kk * 32);
          acc[n] = __builtin_amdgcn_mfma_f32_16x16x32_bf16(a, bh, acc[n], 0, 0, 0);
          bf16x8 bl = *(const bf16x8*)(Bl + (size_t)(n * 16) * KDIM + kk * 32);
          acc[n] = __builtin_amdgcn_mfma_f32_16x16x32_bf16(a, bl, acc[n], 0, 0, 0);
        }
      }
#pragma unroll
      for (int n = 0; n < 2; ++n)
#pragma unroll
        for (int r = 0; r < 4; ++r)
          sm.dbl[mt * 16 + lhi * 4 + r][nh * 32 + n * 16 + l15] = acc[n][r];
    }
    __syncthreads();
    {   // softmax over j (in-register b-logits)
      const int i0b = q * 64;
      const int il = t >> 3, jc = (t & 7) * 8;
      const int ig = i0b + il;
      f32x4 ub0 = *(const f32x4*)(ubg + (size_t)b * JCAP + jc);
      f32x4 ub1 = *(const f32x4*)(ubg + (size_t)b * JCAP + jc + 4);
      const float ubv[8] = {ub0.x, ub0.y, ub0.z, ub0.w, ub1.x, ub1.y, ub1.z, ub1.w};
      float bn[8];
#pragma unroll
      for (int e = 0; e < 8; ++e) {
        float bold = (pass == 1)
            ? Binit[((size_t)(b * JCAP + jc + e)) * ICAP + ig]
            : blogreg[e];
        bn[e] = bold + sm.dbl[il][jc + e] + ubv[e];
        blogreg[e] = bn[e];
      }
      float mx = bn[0];
#pragma unroll
      for (int e = 1; e < 8; ++e) mx = fmaxf(mx, bn[e]);
      mx = fmaxf(mx, __shfl_xor(mx, 1, 64));
      mx = fmaxf(mx, __shfl_xor(mx, 2, 64));
      mx = fmaxf(mx, __shfl_xor(mx, 4, 64));
      float e8[8], se = 0.f;
#pragma unroll
      for (int e = 0; e < 8; ++e) { e8[e] = __expf(bn[e] - mx); se += e8[e]; }
      se += __shfl_xor(se, 1, 64);
      se += __shfl_xor(se, 2, 64);
      se += __shfl_xor(se, 4, 64);
      const float inv = 1.0f / se;
#pragma unroll
      for (int e = 0; e < 8; ++e) sm.dbl[il][jc + e] = e8[e] * inv;
    }
    __syncthreads();
    {   // transpose-pack c -> cm + cpart
      const int i0b = q * 64;
      const int j2 = t >> 3, ic8 = (t & 7) * 8;
      float csump = 0.f;
      unsigned pk[4];
#pragma unroll
      for (int h = 0; h < 4; ++h) {
        float lo = sm.dbl[ic8 + 2 * h][j2];
        float hi = sm.dbl[ic8 + 2 * h + 1][j2];
        csump += lo + hi;
        pk[h] = (unsigned)f2bf(lo) | ((unsigned)f2bf(hi) << 16);
      }
      uint4 sv; sv.x = pk[0]; sv.y = pk[1]; sv.z = pk[2]; sv.w = pk[3];
      *(uint4*)(cm + ((size_t)(b * JCAP + j2)) * ICAP + i0b + ic8) = sv;
      csump += __shfl_xor(csump, 1, 64);
      csump += __shfl_xor(csump, 2, 64);
      csump += __shfl_xor(csump, 4, 64);
      if ((t & 7) == 0) cpart[((size_t)(b * 4 + q)) * JCAP + j2] = csump;
    }
    group_barrier(gcnt, 4 * (2 * pass + 1));  // 12, 20
  }
}

// ---------------------------------------------------------------------------
extern "C" void kernel_launch(void* const* d_in, const int* in_sizes, int n_in,
                              void* d_out, int out_size, void* d_ws, size_t ws_size,
                              hipStream_t stream) {
  const float* x  = (const float*)d_in[0];
  const float* bi = (const float*)d_in[1];
  const float* W  = (const float*)d_in[2];
  const float* Wb = (const float*)d_in[3];
  float* out = (float*)d_out;

  char* ws = (char*)d_ws;
  const size_t MiB = 1024 * 1024;
  unsigned short* xT  = (unsigned short*)(ws + 0 * MiB);    // 8 MiB
  unsigned short* xKI = (unsigned short*)(ws + 8 * MiB);    // 8 MiB
  unsigned short* cm  = (unsigned short*)(ws + 16 * MiB);   // 2 MiB
  unsigned short* Uhi = (unsigned short*)(ws + 18 * MiB);   // 2 MiB
  unsigned short* Ulo = (unsigned short*)(ws + 20 * MiB);   // 2 MiB
  float* cpart        = (float*)(ws + 22 * MiB);            // 64 KiB
  float* ubg          = (float*)(ws + 23 * MiB);            // 16 KiB
  int*   cnt          = (int*)(ws + 24 * MiB);              // 4 KiB

  hipMemsetAsync(cnt, 0, BS * 16 * sizeof(int), stream);
  mega<<<dim3(256), dim3(512), 0, stream>>>(x, bi, W, Wb, xT, xKI, cm,
                                            Uhi, Ulo, cpart, ubg, cnt, out);
}